// Round 5
// baseline (146.205 us; speedup 1.0000x reference)
//
#include <hip/hip_runtime.h>

#define IN_DIM 784
#define NDB 25                 // dim-blocks of 32 (784 -> 800 padded)
#define NUNITS (NDB*9)         // 225 k-units of 32 (32 dims x one c-plane)
#define BATCH 16384
#define NOUTC 160              // HEADS*OUT_DIM
#define HEADS 10
#define KSPLIT 4
#define ROWB 584               // 9 c-planes*64B = 576 + 8 pad (dw stride 146 = 18 mod 32 -> bank floor)
#define CHUNKB (64*ROWB)       // 37376

typedef __attribute__((ext_vector_type(8))) short bf16x8;
typedef __attribute__((ext_vector_type(4))) float f32x4;
typedef __attribute__((ext_vector_type(16))) float f32x16;
typedef __attribute__((ext_vector_type(4))) unsigned int u32x4;

__device__ __forceinline__ unsigned short f2bf(float f) {
    unsigned u = __builtin_bit_cast(unsigned, f);
    unsigned r = 0x7FFFu + ((u >> 16) & 1u);
    return (unsigned short)((u + r) >> 16);
}

// ---------------- weight packing: W -> 32x32x16 MFMA B-fragment layout -------
// unit kc = db*9 + c (32 dims x c-plane); fragment f = (kc*2 + kh)*5 + nt.
// B-frag (K=16 x N=32): lane l elem j: k-in-step = (l>>5)*8 + j  -> d = db*32 + kh*16 + (l>>5)*8 + j
//                        n = nt*32 + (l&31)
// 1/6 spline constant folded here (eval omits it).
__global__ void k_wprep(const float* __restrict__ coef, const float* __restrict__ scale_base,
                        const float* __restrict__ scale_sp, const float* __restrict__ mask,
                        unsigned short* __restrict__ Wp) {
    int tid = blockIdx.x * blockDim.x + threadIdx.x;
    if (tid >= NUNITS * 32 * NOUTC) return;     // 1,152,000
    int frag = tid >> 9;
    int rem  = tid & 511;
    int l = rem >> 3, j = rem & 7;
    int nt = frag % 5;
    int t2 = frag / 5;
    int kh = t2 & 1;
    int kc = t2 >> 1;
    int db = kc / 9, c = kc - db * 9;
    int d = db * 32 + kh * 16 + ((l >> 5) << 3) + j;
    int n = nt * 32 + (l & 31);
    float v = 0.f;
    if (d < IN_DIM) {
        int h = n >> 4, o = n & 15;
        size_t base = ((size_t)h * IN_DIM + d) * 16 + o;
        float m = mask[base];
        v = (c == 0) ? scale_base[base] * m
                     : coef[base * 8 + (c - 1)] * scale_sp[base] * m * 0.16666667f;
    }
    Wp[tid] = f2bf(v);
}

// ---------------- fused feature-gen (LDS scatter) + 32x32 GEMM ---------------
// Block = 128 threads = 2 waves; wave = kh (K-half of each 32-k unit).
// Per unit per wave: 2 ds_read_b128 (A rg0/rg1), 5 B-frag loads, 10 MFMA.
// Block totals per unit: A-reads 4 (= data volume), B-loads 10 (= data volume).
__global__ void __launch_bounds__(128, 2) k_fused(const float* __restrict__ x,
                                                  const float* __restrict__ gridp,
                                                  const unsigned short* __restrict__ Wp,
                                                  float* __restrict__ part) {
    __shared__ char ldsb[CHUNKB];
    const int tid = threadIdx.x;
    const int l = tid & 63, kh = tid >> 6;
    const int la = l & 31, lb = l >> 5;
    const int row0g = blockIdx.x * 64;
    const int y = blockIdx.y;
    const int db0 = (y * NDB) >> 2, db1 = ((y + 1) * NDB) >> 2;

    const float g0 = gridp[0];
    const float ih = 1.f / (gridp[1] - g0);

    f32x16 acc0[5], acc1[5];   // [nt] for rg=0 / rg=1 (this wave's kh-partial)
    #pragma unroll
    for (int i = 0; i < 5; ++i) {
        #pragma unroll
        for (int jj = 0; jj < 16; ++jj) { acc0[i][jj] = 0.f; acc1[i][jj] = 0.f; }
    }

    const int sd = tid & 31;       // dim-in-block
    const int srow0 = tid >> 5;    // 0..3
    const char* aAddr = ldsb + la * ROWB + kh * 32 + lb * 16;
    const bf16x8* Bl = (const bf16x8*)Wp + l;

    for (int db = db0; db < db1; ++db) {
        // ---- zero-fill chunk (b128, linear) ----
        const u32x4 z4 = (u32x4){0u, 0u, 0u, 0u};
        #pragma unroll
        for (int i = 0; i < 19; ++i) {
            int off = (i * 128 + tid) * 16;
            if (off < CHUNKB) *(u32x4*)(ldsb + off) = z4;
        }
        __syncthreads();

        // ---- eval + scatter: 64 rows x 32 dims over 128 threads ----
        const int d = db * 32 + sd;
        const bool valid = d < IN_DIM;
        const float* xp = x + (size_t)row0g * IN_DIM + d;
        #pragma unroll 4
        for (int it = 0; it < 16; ++it) {
            const int row = it * 4 + srow0;
            float xv = valid ? xp[(size_t)row * IN_DIM] : 0.f;
            const float u = (xv - g0) * ih;
            const float fm = floorf(u);
            const int m = (int)fm;
            const float t = u - fm;
            const float w0 = t * t * t;                               // j = m   (x6)
            const float w1 = fmaf(fmaf(fmaf(-3.f, t, 3.f), t, 3.f), t, 1.f); // j=m-1
            const float w2 = fmaf(fmaf(3.f, t, -6.f) * t, t, 4.f);    // j = m-2
            const float omt = 1.f - t;
            const float w3 = omt * omt * omt;                         // j = m-3
            const float den = 1.f + __expf(-xv);
            float inv; asm("v_rcp_f32 %0, %1" : "=v"(inv) : "v"(den));
            const float sil = xv * inv;
            if (valid) {
                char* rp = ldsb + row * ROWB;
                *(unsigned short*)(rp + sd * 2) = f2bf(sil);          // c = 0
                #pragma unroll
                for (int s = 0; s < 4; ++s) {
                    const int j = m - s;
                    const float w = (s == 0) ? w0 : (s == 1) ? w1 : (s == 2) ? w2 : w3;
                    if ((unsigned)j <= 7u)
                        *(unsigned short*)(rp + (j + 1) * 64 + sd * 2) = f2bf(w);
                }
            }
        }
        __syncthreads();

        // ---- MFMA phase: 9 units; this wave does K-half kh of each ----
        const size_t ub = (size_t)(db * 9) * 10 * 64;   // fragment base (in bf16x8)
        #pragma unroll
        for (int c = 0; c < 9; ++c) {
            const size_t bi = ub + (size_t)((c * 2 + kh) * 5) * 64;
            const bf16x8 b0 = Bl[bi];
            const bf16x8 b1 = Bl[bi + 64];
            const bf16x8 b2 = Bl[bi + 128];
            const bf16x8 b3 = Bl[bi + 192];
            const bf16x8 b4 = Bl[bi + 256];
            const bf16x8 a0 = *(const bf16x8*)(aAddr + c * 64);
            const bf16x8 a1 = *(const bf16x8*)(aAddr + 32 * ROWB + c * 64);
            acc0[0] = __builtin_amdgcn_mfma_f32_32x32x16_bf16(a0, b0, acc0[0], 0, 0, 0);
            acc1[0] = __builtin_amdgcn_mfma_f32_32x32x16_bf16(a1, b0, acc1[0], 0, 0, 0);
            acc0[1] = __builtin_amdgcn_mfma_f32_32x32x16_bf16(a0, b1, acc0[1], 0, 0, 0);
            acc1[1] = __builtin_amdgcn_mfma_f32_32x32x16_bf16(a1, b1, acc1[1], 0, 0, 0);
            acc0[2] = __builtin_amdgcn_mfma_f32_32x32x16_bf16(a0, b2, acc0[2], 0, 0, 0);
            acc1[2] = __builtin_amdgcn_mfma_f32_32x32x16_bf16(a1, b2, acc1[2], 0, 0, 0);
            acc0[3] = __builtin_amdgcn_mfma_f32_32x32x16_bf16(a0, b3, acc0[3], 0, 0, 0);
            acc1[3] = __builtin_amdgcn_mfma_f32_32x32x16_bf16(a1, b3, acc1[3], 0, 0, 0);
            acc0[4] = __builtin_amdgcn_mfma_f32_32x32x16_bf16(a0, b4, acc0[4], 0, 0, 0);
            acc1[4] = __builtin_amdgcn_mfma_f32_32x32x16_bf16(a1, b4, acc1[4], 0, 0, 0);
        }
        __syncthreads();
    }

    // ---- cross-kh reduction (2 passes over rg) + store ----
    // C/D layout (32x32): col = nt*32 + (l&31), row = (reg&3) + 8*(reg>>2) + 4*(l>>5)
    float* pp = part + (size_t)y * BATCH * NOUTC;
#define REDUCE_STORE(ACC, RG)                                                   \
    {                                                                           \
        if (kh == 1) {                                                          \
            _Pragma("unroll")                                                   \
            for (int nt = 0; nt < 5; ++nt) {                                    \
                _Pragma("unroll")                                               \
                for (int g = 0; g < 4; ++g) {                                   \
                    f32x4 v = (f32x4){ACC[nt][g*4+0], ACC[nt][g*4+1],           \
                                      ACC[nt][g*4+2], ACC[nt][g*4+3]};          \
                    *(f32x4*)(ldsb + nt * 5120 + l * 80 + g * 16) = v;          \
                }                                                               \
            }                                                                   \
        }                                                                       \
        __syncthreads();                                                        \
        if (kh == 0) {                                                          \
            _Pragma("unroll")                                                   \
            for (int nt = 0; nt < 5; ++nt) {                                    \
                _Pragma("unroll")                                               \
                for (int g = 0; g < 4; ++g) {                                   \
                    f32x4 v = *(const f32x4*)(ldsb + nt * 5120 + l * 80 + g * 16); \
                    _Pragma("unroll")                                           \
                    for (int ii = 0; ii < 4; ++ii) {                            \
                        const int r = g * 4 + ii;                               \
                        const int rl = (r & 3) + 8 * (r >> 2) + 4 * lb;         \
                        pp[(size_t)(row0g + RG * 32 + rl) * NOUTC + nt * 32 + la] \
                            = ACC[nt][r] + v[ii];                               \
                    }                                                           \
                }                                                               \
            }                                                                   \
        }                                                                       \
        __syncthreads();                                                        \
    }
    REDUCE_STORE(acc0, 0)
    REDUCE_STORE(acc1, 1)
#undef REDUCE_STORE
}

// ---------------- epilogue MLP: sum partials, tanh -> 16x8 -> tanh -> 8x1 ----
__global__ void k_epi(const float* __restrict__ part, const float* __restrict__ w1,
                      const float* __restrict__ b1, const float* __restrict__ w2,
                      const float* __restrict__ b2, float* __restrict__ out) {
    int t = blockIdx.x * blockDim.x + threadIdx.x;
    if (t >= BATCH * HEADS) return;
    int b = t / HEADS;
    int h = t - b * HEADS;
    const f32x4* P = (const f32x4*)part;
    const int vbase = b * (NOUTC / 4) + h * 4;
    float y[16];
    #pragma unroll
    for (int c4 = 0; c4 < 4; ++c4) {
        f32x4 v = P[vbase + c4];
        #pragma unroll
        for (int s = 1; s < KSPLIT; ++s) {
            f32x4 v2 = P[(size_t)s * BATCH * (NOUTC / 4) + vbase + c4];
            v.x += v2.x; v.y += v2.y; v.z += v2.z; v.w += v2.w;
        }
        y[c4 * 4 + 0] = tanhf(v.x); y[c4 * 4 + 1] = tanhf(v.y);
        y[c4 * 4 + 2] = tanhf(v.z); y[c4 * 4 + 3] = tanhf(v.w);
    }
    float oacc = b2[h];
    #pragma unroll
    for (int p = 0; p < 8; ++p) {
        float a = b1[h * 8 + p];
        const float* wr = w1 + ((size_t)h * 8 + p) * 16;
        #pragma unroll
        for (int o = 0; o < 16; ++o) a = fmaf(y[o], wr[o], a);
        oacc = fmaf(tanhf(a), w2[h * 8 + p], oacc);
    }
    out[t] = oacc;
}

extern "C" void kernel_launch(void* const* d_in, const int* in_sizes, int n_in,
                              void* d_out, int out_size, void* d_ws, size_t ws_size,
                              hipStream_t stream) {
    const float* x          = (const float*)d_in[0];
    const float* gridp      = (const float*)d_in[1];
    const float* coef       = (const float*)d_in[2];
    const float* scale_base = (const float*)d_in[3];
    const float* scale_sp   = (const float*)d_in[4];
    const float* mask       = (const float*)d_in[5];
    const float* w1         = (const float*)d_in[6];
    const float* b1         = (const float*)d_in[7];
    const float* w2         = (const float*)d_in[8];
    const float* b2         = (const float*)d_in[9];
    float* out = (float*)d_out;

    char* ws = (char*)d_ws;
    float* part        = (float*)ws;                          // 4*16384*160*4 = 41,943,040 B
    unsigned short* Wp = (unsigned short*)(ws + 41943040);    // 225*32*160*2  =  2,304,000 B

    k_wprep<<<dim3((NUNITS * 32 * NOUTC + 255) / 256), dim3(256), 0, stream>>>(coef, scale_base, scale_sp, mask, Wp);
    k_fused<<<dim3(BATCH / 64, KSPLIT), dim3(128), 0, stream>>>(x, gridp, Wp, part);
    k_epi  <<<dim3((BATCH * HEADS + 255) / 256), dim3(256), 0, stream>>>(part, w1, b1, w2, b2, out);
}

// Round 6
// 132.145 us; speedup vs baseline: 1.1064x; 1.1064x over previous
//
#include <hip/hip_runtime.h>

#define IN_DIM 784
#define NDB 25                 // dim-blocks of 32 (784 -> 800 padded)
#define NUNITS (NDB*9)         // 225 k-units of 32 (32 dims x one c-plane)
#define BATCH 16384
#define NOUTC 160              // HEADS*OUT_DIM
#define HEADS 10
#define KSPLIT 4
#define ROWB 584               // 9 c-planes*64B = 576 + 8 pad (dw stride 146 = 18 mod 32 -> A-read bank floor)
#define CHUNKB (64*ROWB)       // 37376; double-buffered

typedef __attribute__((ext_vector_type(8))) short bf16x8;
typedef __attribute__((ext_vector_type(4))) float f32x4;
typedef __attribute__((ext_vector_type(16))) float f32x16;

__device__ __forceinline__ unsigned short f2bf(float f) {
    unsigned u = __builtin_bit_cast(unsigned, f);
    unsigned r = 0x7FFFu + ((u >> 16) & 1u);
    return (unsigned short)((u + r) >> 16);
}

// ---------------- weight packing: W -> 32x32x16 MFMA B-fragment layout -------
// unit kc = db*9 + c; fragment f = (kc*2 + kh)*5 + nt.
// B-frag: lane l elem j: d = db*32 + kh*16 + (l>>5)*8 + j ; n = nt*32 + (l&31)
// 1/6 spline constant folded here. (verified r5)
__global__ void k_wprep(const float* __restrict__ coef, const float* __restrict__ scale_base,
                        const float* __restrict__ scale_sp, const float* __restrict__ mask,
                        unsigned short* __restrict__ Wp) {
    int tid = blockIdx.x * blockDim.x + threadIdx.x;
    if (tid >= NUNITS * 32 * NOUTC) return;     // 1,152,000
    int frag = tid >> 9;
    int rem  = tid & 511;
    int l = rem >> 3, j = rem & 7;
    int nt = frag % 5;
    int t2 = frag / 5;
    int kh = t2 & 1;
    int kc = t2 >> 1;
    int db = kc / 9, c = kc - db * 9;
    int d = db * 32 + kh * 16 + ((l >> 5) << 3) + j;
    int n = nt * 32 + (l & 31);
    float v = 0.f;
    if (d < IN_DIM) {
        int h = n >> 4, o = n & 15;
        size_t base = ((size_t)h * IN_DIM + d) * 16 + o;
        float m = mask[base];
        v = (c == 0) ? scale_base[base] * m
                     : coef[base * 8 + (c - 1)] * scale_sp[base] * m * 0.16666667f;
    }
    Wp[tid] = f2bf(v);
}

// ---------------- fused: dbuf LDS, dense scatter, c-split waves --------------
__global__ void __launch_bounds__(256, 2) k_fused(const float* __restrict__ x,
                                                  const float* __restrict__ gridp,
                                                  const unsigned short* __restrict__ Wp,
                                                  float* __restrict__ part) {
    __shared__ char ldsb[2 * CHUNKB];
    const int tid = threadIdx.x;
    const int l = tid & 63, wid = tid >> 6;
    const int la = l & 31, lb = l >> 5;
    const int sd = tid & 31, srow0 = tid >> 5;      // scatter: dim-in-block, row group 0..7
    const int row0g = blockIdx.x * 64;
    const int y = blockIdx.y;
    const int db0 = (y * NDB) >> 2, db1 = ((y + 1) * NDB) >> 2;

    const float g0 = gridp[0];
    const float ih = 1.f / (gridp[1] - g0);
    const float nihg0 = -g0 * ih;

    // per-wave c-partition {3,2,2,2}
    const int cbeg = (wid == 0) ? 0 : (wid == 1) ? 3 : (wid == 2) ? 5 : 7;
    const int ccnt = (wid == 0) ? 3 : 2;

    f32x16 acc[2][5];
    #pragma unroll
    for (int rg = 0; rg < 2; ++rg)
        #pragma unroll
        for (int nt = 0; nt < 5; ++nt)
            #pragma unroll
            for (int j = 0; j < 16; ++j) acc[rg][nt][j] = 0.f;

    const char* wpb = (const char*)Wp;
    float xv[8];

    auto loadX = [&](int db) {
        const int d = db * 32 + sd;
        const int dc = d < IN_DIM ? d : IN_DIM - 1;   // clamp; junk cols hit zeroed W
        const float* xp = x + (size_t)(row0g + srow0) * IN_DIM + dc;
        #pragma unroll
        for (int it = 0; it < 8; ++it) xv[it] = xp[(size_t)it * 8 * IN_DIM];
    };

    // dense thread-owned scatter: writes ALL 9 c-slots of (row, sd) -> stale buffer safe
    auto evalStep = [&](int it, char* sbuf) {
        const float v = xv[it];
        const float u = fmaf(v, ih, nihg0);
        const float fm = floorf(u);
        const int m = (int)fm;
        const float t = u - fm;
        const float t2 = t * t;
        const float w0 = t2 * t;
        const float w1 = fmaf(fmaf(fmaf(-3.f, t, 3.f), t, 3.f), t, 1.f);
        const float w2 = fmaf(fmaf(3.f, t, -6.f) * t, t, 4.f);
        const float omt = 1.f - t;
        const float w3 = omt * omt * omt;
        const float den = 1.f + __expf(-v);
        float inv; asm("v_rcp_f32 %0, %1" : "=v"(inv) : "v"(den));
        const float sil = v * inv;
        char* rb = sbuf + (it * 8 + srow0) * ROWB + sd * 2;
        *(unsigned short*)rb = f2bf(sil);                       // c = 0
        #pragma unroll
        for (int s = 0; s < 8; ++s) {                           // j=(m-s)&7: permutation of [0,7]
            const int ms = m - s;
            const unsigned off = (((unsigned)ms & 7u) << 6) + 64u;
            float wv = 0.f;
            if (s <= 3) {
                const float wsel = (s == 0) ? w0 : (s == 1) ? w1 : (s == 2) ? w2 : w3;
                wv = ((unsigned)ms <= 7u) ? wsel : 0.f;
            }
            *(unsigned short*)(rb + off) = f2bf(wv);
        }
    };

    auto cStep = [&](int ci, const char* rbuf, const char* bbase) {
        if (ci < ccnt) {
            const int c = cbeg + ci;
            const char* ab = rbuf + la * ROWB + lb * 16 + c * 64;
            const bf16x8 a00 = *(const bf16x8*)(ab);                  // rg0 kh0
            const bf16x8 a01 = *(const bf16x8*)(ab + 32);             // rg0 kh1
            const bf16x8 a10 = *(const bf16x8*)(ab + 32 * ROWB);      // rg1 kh0
            const bf16x8 a11 = *(const bf16x8*)(ab + 32 * ROWB + 32); // rg1 kh1
            const char* bc = bbase + c * 10240 + l * 16;
            #pragma unroll
            for (int nt = 0; nt < 5; ++nt) {
                const bf16x8 b = *(const bf16x8*)(bc + nt * 1024);
                acc[0][nt] = __builtin_amdgcn_mfma_f32_32x32x16_bf16(a00, b, acc[0][nt], 0, 0, 0);
                acc[1][nt] = __builtin_amdgcn_mfma_f32_32x32x16_bf16(a10, b, acc[1][nt], 0, 0, 0);
            }
            #pragma unroll
            for (int nt = 0; nt < 5; ++nt) {
                const bf16x8 b = *(const bf16x8*)(bc + 5120 + nt * 1024);
                acc[0][nt] = __builtin_amdgcn_mfma_f32_32x32x16_bf16(a01, b, acc[0][nt], 0, 0, 0);
                acc[1][nt] = __builtin_amdgcn_mfma_f32_32x32x16_bf16(a11, b, acc[1][nt], 0, 0, 0);
            }
        }
    };

    // prologue: stage chunk db0 into buf0
    loadX(db0);
    #pragma unroll
    for (int it = 0; it < 8; ++it) evalStep(it, ldsb);
    __syncthreads();

    int p = 0;
    for (int db = db0; db < db1; ++db) {
        const bool hasN = (db + 1) < db1;
        char* sbuf = ldsb + (p ^ 1) * CHUNKB;
        const char* rbuf = ldsb + p * CHUNKB;
        const char* bbase = wpb + (size_t)db * 92160;   // 9c * 10frag * 1024B
        if (hasN) loadX(db + 1);
        if (hasN) { evalStep(0, sbuf); evalStep(1, sbuf); }
        cStep(0, rbuf, bbase);
        if (hasN) { evalStep(2, sbuf); evalStep(3, sbuf); }
        cStep(1, rbuf, bbase);
        if (hasN) { evalStep(4, sbuf); evalStep(5, sbuf); }
        cStep(2, rbuf, bbase);
        if (hasN) { evalStep(6, sbuf); evalStep(7, sbuf); }
        __syncthreads();
        p ^= 1;
    }

    // ---- cross-wave (c-part) reduction, nt-chunked; then w0 stores ----------
    // region layout: lane stride 100 dwords (bank-spread), slot = (rg*ncnt+ni)*4+g
    float* R1 = (float*)ldsb;
    float* R3 = (float*)ldsb + 6400;          // 25,600 B regions; 51,200 <= 74,752
    float* pp = part + (size_t)y * BATCH * NOUTC;
    #pragma unroll
    for (int ntg = 0; ntg < 2; ++ntg) {
        const int n0 = (ntg == 0) ? 0 : 3;
        const int ncnt = (ntg == 0) ? 3 : 2;
        if (wid == 1 || wid == 3) {
            float* R = (wid == 1) ? R1 : R3;
            #pragma unroll
            for (int rg = 0; rg < 2; ++rg)
                #pragma unroll
                for (int ni = 0; ni < 3; ++ni) if (ni < ncnt)
                    #pragma unroll
                    for (int g = 0; g < 4; ++g) {
                        f32x4 v = (f32x4){acc[rg][n0 + ni][g * 4 + 0], acc[rg][n0 + ni][g * 4 + 1],
                                          acc[rg][n0 + ni][g * 4 + 2], acc[rg][n0 + ni][g * 4 + 3]};
                        *(f32x4*)(R + l * 100 + ((rg * ncnt + ni) * 4 + g) * 4) = v;
                    }
        }
        __syncthreads();
        if (wid == 0 || wid == 2) {
            const float* R = (wid == 0) ? R1 : R3;
            #pragma unroll
            for (int rg = 0; rg < 2; ++rg)
                #pragma unroll
                for (int ni = 0; ni < 3; ++ni) if (ni < ncnt)
                    #pragma unroll
                    for (int g = 0; g < 4; ++g) {
                        f32x4 v = *(const f32x4*)(R + l * 100 + ((rg * ncnt + ni) * 4 + g) * 4);
                        #pragma unroll
                        for (int j = 0; j < 4; ++j) acc[rg][n0 + ni][g * 4 + j] += v[j];
                    }
        }
        __syncthreads();
        if (wid == 2) {
            #pragma unroll
            for (int rg = 0; rg < 2; ++rg)
                #pragma unroll
                for (int ni = 0; ni < 3; ++ni) if (ni < ncnt)
                    #pragma unroll
                    for (int g = 0; g < 4; ++g) {
                        f32x4 v = (f32x4){acc[rg][n0 + ni][g * 4 + 0], acc[rg][n0 + ni][g * 4 + 1],
                                          acc[rg][n0 + ni][g * 4 + 2], acc[rg][n0 + ni][g * 4 + 3]};
                        *(f32x4*)(R1 + l * 100 + ((rg * ncnt + ni) * 4 + g) * 4) = v;
                    }
        }
        __syncthreads();
        if (wid == 0) {
            // C/D layout: col = nt*32 + la, row = (r&3) + 8*(r>>2) + 4*lb
            #pragma unroll
            for (int rg = 0; rg < 2; ++rg)
                #pragma unroll
                for (int ni = 0; ni < 3; ++ni) if (ni < ncnt)
                    #pragma unroll
                    for (int g = 0; g < 4; ++g) {
                        f32x4 v = *(const f32x4*)(R1 + l * 100 + ((rg * ncnt + ni) * 4 + g) * 4);
                        #pragma unroll
                        for (int j = 0; j < 4; ++j) {
                            const int r = g * 4 + j;
                            const int rl = (r & 3) + 8 * (r >> 2) + 4 * lb;
                            pp[(size_t)(row0g + rg * 32 + rl) * NOUTC + (n0 + ni) * 32 + la]
                                = acc[rg][n0 + ni][r] + v[j];
                        }
                    }
        }
        __syncthreads();
    }
}

// ---------------- epilogue MLP: sum partials, tanh -> 16x8 -> tanh -> 8x1 ----
__global__ void k_epi(const float* __restrict__ part, const float* __restrict__ w1,
                      const float* __restrict__ b1, const float* __restrict__ w2,
                      const float* __restrict__ b2, float* __restrict__ out) {
    int t = blockIdx.x * blockDim.x + threadIdx.x;
    if (t >= BATCH * HEADS) return;
    int b = t / HEADS;
    int h = t - b * HEADS;
    const f32x4* P = (const f32x4*)part;
    const int vbase = b * (NOUTC / 4) + h * 4;
    float y[16];
    #pragma unroll
    for (int c4 = 0; c4 < 4; ++c4) {
        f32x4 v = P[vbase + c4];
        #pragma unroll
        for (int s = 1; s < KSPLIT; ++s) {
            f32x4 v2 = P[(size_t)s * BATCH * (NOUTC / 4) + vbase + c4];
            v.x += v2.x; v.y += v2.y; v.z += v2.z; v.w += v2.w;
        }
        y[c4 * 4 + 0] = tanhf(v.x); y[c4 * 4 + 1] = tanhf(v.y);
        y[c4 * 4 + 2] = tanhf(v.z); y[c4 * 4 + 3] = tanhf(v.w);
    }
    float oacc = b2[h];
    #pragma unroll
    for (int p = 0; p < 8; ++p) {
        float a = b1[h * 8 + p];
        const float* wr = w1 + ((size_t)h * 8 + p) * 16;
        #pragma unroll
        for (int o = 0; o < 16; ++o) a = fmaf(y[o], wr[o], a);
        oacc = fmaf(tanhf(a), w2[h * 8 + p], oacc);
    }
    out[t] = oacc;
}

extern "C" void kernel_launch(void* const* d_in, const int* in_sizes, int n_in,
                              void* d_out, int out_size, void* d_ws, size_t ws_size,
                              hipStream_t stream) {
    const float* x          = (const float*)d_in[0];
    const float* gridp      = (const float*)d_in[1];
    const float* coef       = (const float*)d_in[2];
    const float* scale_base = (const float*)d_in[3];
    const float* scale_sp   = (const float*)d_in[4];
    const float* mask       = (const float*)d_in[5];
    const float* w1         = (const float*)d_in[6];
    const float* b1         = (const float*)d_in[7];
    const float* w2         = (const float*)d_in[8];
    const float* b2         = (const float*)d_in[9];
    float* out = (float*)d_out;

    char* ws = (char*)d_ws;
    float* part        = (float*)ws;                          // 4*16384*160*4 = 41,943,040 B
    unsigned short* Wp = (unsigned short*)(ws + 41943040);    // 225*32*160*2  =  2,304,000 B

    k_wprep<<<dim3((NUNITS * 32 * NOUTC + 255) / 256), dim3(256), 0, stream>>>(coef, scale_base, scale_sp, mask, Wp);
    k_fused<<<dim3(BATCH / 64, KSPLIT), dim3(256), 0, stream>>>(x, gridp, Wp, part);
    k_epi  <<<dim3((BATCH * HEADS + 255) / 256), dim3(256), 0, stream>>>(part, w1, b1, w2, b2, out);
}

// Round 7
// 129.311 us; speedup vs baseline: 1.1306x; 1.0219x over previous
//
#include <hip/hip_runtime.h>

#define IN_DIM 784
#define NDB 25                 // dim-blocks of 32 (784 -> 800 padded)
#define NUNITS (NDB*9)         // 225 k-units of 32 (32 dims x one c-plane)
#define BATCH 16384
#define NOUTC 160              // HEADS*OUT_DIM
#define NT16 10                // 16-wide n-tiles
#define HEADS 10
#define KSPLIT 4
#define ROWB 584               // 9 c-planes*64B = 576 + 8 pad (dw stride 146 = 18 mod 32 -> A-read bank floor)
#define CHUNKB (64*ROWB)       // 37376, single buffer -> 4 blocks/CU by LDS

typedef __attribute__((ext_vector_type(8))) short bf16x8;
typedef __attribute__((ext_vector_type(4))) float f32x4;

__device__ __forceinline__ unsigned short f2bf(float f) {
    unsigned u = __builtin_bit_cast(unsigned, f);
    unsigned r = 0x7FFFu + ((u >> 16) & 1u);
    return (unsigned short)((u + r) >> 16);
}

// ---------------- weight packing: W -> 16x16x32 MFMA B-fragment layout -------
// unit kc = db*9 + c covers (d = db*32 + kk, type c), kk = 0..31.
// Fragment f = kc*10 + nt. Lane l elem j: kk = (l>>4)*8 + j ; n = nt*16 + (l&15).
// 1/6 spline constant folded here (eval omits it). [r4-verified layout + r5 fold]
__global__ void k_wprep(const float* __restrict__ coef, const float* __restrict__ scale_base,
                        const float* __restrict__ scale_sp, const float* __restrict__ mask,
                        unsigned short* __restrict__ Wp) {
    int tid = blockIdx.x * blockDim.x + threadIdx.x;
    if (tid >= NUNITS * 32 * NOUTC) return;     // 1,152,000
    int frag = tid >> 9;
    int rem  = tid & 511;
    int l = rem >> 3, j = rem & 7;
    int kc = frag / 10, nt = frag - kc * 10;
    int db = kc / 9, c = kc - db * 9;
    int kk = ((l >> 4) << 3) + j;
    int d = db * 32 + kk;
    int n = nt * 16 + (l & 15);
    float v = 0.f;
    if (d < IN_DIM) {
        int h = n >> 4, o = n & 15;
        size_t base = ((size_t)h * IN_DIM + d) * 16 + o;
        float m = mask[base];
        v = (c == 0) ? scale_base[base] * m
                     : coef[base * 8 + (c - 1)] * scale_sp[base] * m * 0.16666667f;
    }
    Wp[tid] = f2bf(v);
}

// ---------------- fused feature-gen (dense LDS scatter) + 16x16 GEMM ---------
// 512 threads = 8 waves; wave (rg = wid>>1, nh = wid&1) owns output tile
// rows [rg*16, rg*16+16) x cols [nh*80, nh*80+80)  -> acc = 5 x f32x4 = 20 regs.
// No cross-wave reduction. A-reads x2-dup, B-loads x4-dup (L1-absorbed, r4 regime).
__global__ void __launch_bounds__(512, 4) k_fused(const float* __restrict__ x,
                                                  const float* __restrict__ gridp,
                                                  const unsigned short* __restrict__ Wp,
                                                  float* __restrict__ part) {
    __shared__ char ldsb[CHUNKB];
    const int tid = threadIdx.x;
    const int l = tid & 63, wid = tid >> 6;
    const int rr = l & 15, q = l >> 4;
    const int rg = wid >> 1, nh = wid & 1;
    const int sd = tid & 31, srg = tid >> 5;        // scatter: dim-in-block, row 0..15
    const int row0g = blockIdx.x * 64;
    const int y = blockIdx.y;
    const int db0 = (y * NDB) >> 2, db1 = ((y + 1) * NDB) >> 2;

    const float g0 = gridp[0];
    const float ih = 1.f / (gridp[1] - g0);
    const float nihg0 = -g0 * ih;

    f32x4 acc[5];
    #pragma unroll
    for (int i = 0; i < 5; ++i) acc[i] = (f32x4){0.f, 0.f, 0.f, 0.f};

    const char* wpb = (const char*)Wp;
    float xv[4];

    auto loadX = [&](int db) {
        const int d = db * 32 + sd;
        const int dc = d < IN_DIM ? d : IN_DIM - 1;   // clamp; junk dims hit zeroed W
        const float* xp = x + (size_t)(row0g + srg) * IN_DIM + dc;
        #pragma unroll
        for (int it = 0; it < 4; ++it) xv[it] = xp[(size_t)it * 16 * IN_DIM];
    };

    // dense thread-owned scatter: writes ALL 9 c-slots of (row, sd) -> stale buffer safe
    auto evalScatter = [&]() {
        #pragma unroll
        for (int it = 0; it < 4; ++it) {
            const float v = xv[it];
            const float u = fmaf(v, ih, nihg0);
            const float fm = floorf(u);
            const int m = (int)fm;
            const float t = u - fm;
            const float t2 = t * t;
            const float w0 = t2 * t;
            const float w1 = fmaf(fmaf(fmaf(-3.f, t, 3.f), t, 3.f), t, 1.f);
            const float w2 = fmaf(fmaf(3.f, t, -6.f) * t, t, 4.f);
            const float omt = 1.f - t;
            const float w3 = omt * omt * omt;
            const float den = 1.f + __expf(-v);
            float inv; asm("v_rcp_f32 %0, %1" : "=v"(inv) : "v"(den));
            const float sil = v * inv;
            char* rb = ldsb + (it * 16 + srg) * ROWB + sd * 2;
            *(unsigned short*)rb = f2bf(sil);                   // c = 0
            #pragma unroll
            for (int s = 0; s < 8; ++s) {                       // j=(m-s)&7: permutation of [0,7]
                const int ms = m - s;
                const unsigned off = (((unsigned)ms & 7u) << 6) + 64u;
                float wv = 0.f;
                if (s <= 3) {
                    const float wsel = (s == 0) ? w0 : (s == 1) ? w1 : (s == 2) ? w2 : w3;
                    wv = ((unsigned)ms <= 7u) ? wsel : 0.f;
                }
                *(unsigned short*)(rb + off) = f2bf(wv);
            }
        }
    };

    loadX(db0);
    for (int db = db0; db < db1; ++db) {
        __syncthreads();               // all waves done reading previous chunk
        evalScatter();
        if (db + 1 < db1) loadX(db + 1);   // overlaps with MFMA phase below
        __syncthreads();               // chunk ready

        // MFMA phase: 9 units; 1 A-read + 5 B-loads + 5 MFMA per unit
        const char* arow = ldsb + (rg * 16 + rr) * ROWB + q * 16;
        const char* bb = wpb + (size_t)db * 92160 + nh * 5120 + l * 16;
        #pragma unroll
        for (int c = 0; c < 9; ++c) {
            const bf16x8 a = *(const bf16x8*)(arow + c * 64);
            const char* bc = bb + c * 10240;
            const bf16x8 b0 = *(const bf16x8*)(bc);
            const bf16x8 b1 = *(const bf16x8*)(bc + 1024);
            const bf16x8 b2 = *(const bf16x8*)(bc + 2048);
            const bf16x8 b3 = *(const bf16x8*)(bc + 3072);
            const bf16x8 b4 = *(const bf16x8*)(bc + 4096);
            acc[0] = __builtin_amdgcn_mfma_f32_16x16x32_bf16(a, b0, acc[0], 0, 0, 0);
            acc[1] = __builtin_amdgcn_mfma_f32_16x16x32_bf16(a, b1, acc[1], 0, 0, 0);
            acc[2] = __builtin_amdgcn_mfma_f32_16x16x32_bf16(a, b2, acc[2], 0, 0, 0);
            acc[3] = __builtin_amdgcn_mfma_f32_16x16x32_bf16(a, b3, acc[3], 0, 0, 0);
            acc[4] = __builtin_amdgcn_mfma_f32_16x16x32_bf16(a, b4, acc[4], 0, 0, 0);
        }
    }

    // ---- direct store (no reduction): C/D 16x16: row = q*4+ii, col = rr ----
    float* pp = part + (size_t)y * BATCH * NOUTC;
    #pragma unroll
    for (int ntl = 0; ntl < 5; ++ntl) {
        const int col = (nh * 5 + ntl) * 16 + rr;
        #pragma unroll
        for (int ii = 0; ii < 4; ++ii)
            pp[(size_t)(row0g + rg * 16 + q * 4 + ii) * NOUTC + col] = acc[ntl][ii];
    }
}

// ---------------- epilogue MLP: sum partials, tanh -> 16x8 -> tanh -> 8x1 ----
__global__ void k_epi(const float* __restrict__ part, const float* __restrict__ w1,
                      const float* __restrict__ b1, const float* __restrict__ w2,
                      const float* __restrict__ b2, float* __restrict__ out) {
    int t = blockIdx.x * blockDim.x + threadIdx.x;
    if (t >= BATCH * HEADS) return;
    int b = t / HEADS;
    int h = t - b * HEADS;
    const f32x4* P = (const f32x4*)part;
    const int vbase = b * (NOUTC / 4) + h * 4;
    float y[16];
    #pragma unroll
    for (int c4 = 0; c4 < 4; ++c4) {
        f32x4 v = P[vbase + c4];
        #pragma unroll
        for (int s = 1; s < KSPLIT; ++s) {
            f32x4 v2 = P[(size_t)s * BATCH * (NOUTC / 4) + vbase + c4];
            v.x += v2.x; v.y += v2.y; v.z += v2.z; v.w += v2.w;
        }
        y[c4 * 4 + 0] = tanhf(v.x); y[c4 * 4 + 1] = tanhf(v.y);
        y[c4 * 4 + 2] = tanhf(v.z); y[c4 * 4 + 3] = tanhf(v.w);
    }
    float oacc = b2[h];
    #pragma unroll
    for (int p = 0; p < 8; ++p) {
        float a = b1[h * 8 + p];
        const float* wr = w1 + ((size_t)h * 8 + p) * 16;
        #pragma unroll
        for (int o = 0; o < 16; ++o) a = fmaf(y[o], wr[o], a);
        oacc = fmaf(tanhf(a), w2[h * 8 + p], oacc);
    }
    out[t] = oacc;
}

extern "C" void kernel_launch(void* const* d_in, const int* in_sizes, int n_in,
                              void* d_out, int out_size, void* d_ws, size_t ws_size,
                              hipStream_t stream) {
    const float* x          = (const float*)d_in[0];
    const float* gridp      = (const float*)d_in[1];
    const float* coef       = (const float*)d_in[2];
    const float* scale_base = (const float*)d_in[3];
    const float* scale_sp   = (const float*)d_in[4];
    const float* mask       = (const float*)d_in[5];
    const float* w1         = (const float*)d_in[6];
    const float* b1         = (const float*)d_in[7];
    const float* w2         = (const float*)d_in[8];
    const float* b2         = (const float*)d_in[9];
    float* out = (float*)d_out;

    char* ws = (char*)d_ws;
    float* part        = (float*)ws;                          // 4*16384*160*4 = 41,943,040 B
    unsigned short* Wp = (unsigned short*)(ws + 41943040);    // 225*32*160*2  =  2,304,000 B

    k_wprep<<<dim3((NUNITS * 32 * NOUTC + 255) / 256), dim3(256), 0, stream>>>(coef, scale_base, scale_sp, mask, Wp);
    k_fused<<<dim3(BATCH / 64, KSPLIT), dim3(512), 0, stream>>>(x, gridp, Wp, part);
    k_epi  <<<dim3((BATCH * HEADS + 255) / 256), dim3(256), 0, stream>>>(part, w1, b1, w2, b2, out);
}

// Round 8
// 121.524 us; speedup vs baseline: 1.2031x; 1.0641x over previous
//
#include <hip/hip_runtime.h>

#define IN_DIM 784
#define NDB 25                 // dim-blocks of 32 (784 -> 800 padded)
#define NUNITS (NDB*9)         // 225 k-units of 32 (32 dims x one c-plane)
#define BATCH 16384
#define NOUTC 160              // HEADS*OUT_DIM
#define HEADS 10
#define KSPLIT 4
#define MROWS 128              // rows per block (halves B re-reads vs 64)
#define ROWB 584               // 9 c-planes*64B = 576 + 8 pad (dw stride 146 = 18 mod 32 -> A-read bank floor)
#define CHUNKB (MROWS*ROWB)    // 74752 -> 2 blocks/CU

typedef __attribute__((ext_vector_type(8))) short bf16x8;
typedef __attribute__((ext_vector_type(4))) float f32x4;

__device__ __forceinline__ unsigned short f2bf(float f) {
    unsigned u = __builtin_bit_cast(unsigned, f);
    unsigned r = 0x7FFFu + ((u >> 16) & 1u);
    return (unsigned short)((u + r) >> 16);
}

// ---------------- weight packing: W -> 16x16x32 MFMA B-fragment layout -------
// unit kc = db*9 + c covers (d = db*32 + kk, type c), kk = 0..31.
// Fragment f = kc*10 + nt. Lane l elem j: kk = (l>>4)*8 + j ; n = nt*16 + (l&15).
// 1/6 spline constant folded. [verified r4/r7]
__global__ void k_wprep(const float* __restrict__ coef, const float* __restrict__ scale_base,
                        const float* __restrict__ scale_sp, const float* __restrict__ mask,
                        unsigned short* __restrict__ Wp) {
    int tid = blockIdx.x * blockDim.x + threadIdx.x;
    if (tid >= NUNITS * 32 * NOUTC) return;     // 1,152,000
    int frag = tid >> 9;
    int rem  = tid & 511;
    int l = rem >> 3, j = rem & 7;
    int kc = frag / 10, nt = frag - kc * 10;
    int db = kc / 9, c = kc - db * 9;
    int kk = ((l >> 4) << 3) + j;
    int d = db * 32 + kk;
    int n = nt * 16 + (l & 15);
    float v = 0.f;
    if (d < IN_DIM) {
        int h = n >> 4, o = n & 15;
        size_t base = ((size_t)h * IN_DIM + d) * 16 + o;
        float m = mask[base];
        v = (c == 0) ? scale_base[base] * m
                     : coef[base * 8 + (c - 1)] * scale_sp[base] * m * 0.16666667f;
    }
    Wp[tid] = f2bf(v);
}

// ---------------- fused feature-gen (dense LDS scatter) + 16x16 GEMM ---------
// 512 threads = 8 waves; wave (rp = wid>>1, nh = wid&1) owns rows
// {2rp,2rp+1}*16 x cols [nh*80, nh*80+80): acc = 2x5 f32x4 = 40 VGPR.
// B-loads: 4x dup (rp-waves share nh) but M=128 halves unique traffic;
// explicit next-unit B prefetch hides L2 latency under MFMAs.
__global__ void __launch_bounds__(512, 4) k_fused(const float* __restrict__ x,
                                                  const float* __restrict__ gridp,
                                                  const unsigned short* __restrict__ Wp,
                                                  float* __restrict__ part) {
    __shared__ char ldsb[CHUNKB];
    const int tid = threadIdx.x;
    const int l = tid & 63, wid = tid >> 6;
    const int rr = l & 15, q = l >> 4;
    const int rp = wid >> 1, nh = wid & 1;
    const int sd = tid & 31, srg = tid >> 5;        // scatter: dim-in-block, row 0..15
    const int row0g = blockIdx.x * MROWS;
    const int y = blockIdx.y;
    const int db0 = (y * NDB) >> 2, db1 = ((y + 1) * NDB) >> 2;

    const float g0 = gridp[0];
    const float ih = 1.f / (gridp[1] - g0);
    const float nihg0 = -g0 * ih;

    f32x4 acc[2][5];
    #pragma unroll
    for (int rg = 0; rg < 2; ++rg)
        #pragma unroll
        for (int i = 0; i < 5; ++i) acc[rg][i] = (f32x4){0.f, 0.f, 0.f, 0.f};

    const char* wpb = (const char*)Wp;
    float xv[8];

    auto loadX = [&](int db) {
        const int d = db * 32 + sd;
        const int dc = d < IN_DIM ? d : IN_DIM - 1;   // clamp; junk dims hit zeroed W
        const float* xp = x + (size_t)(row0g + srg) * IN_DIM + dc;
        #pragma unroll
        for (int it = 0; it < 8; ++it) xv[it] = xp[(size_t)it * 16 * IN_DIM];
    };

    // dense thread-owned scatter: writes ALL 9 c-slots of (row, sd); u16 values
    // pre-packed with v_cvt_pk_bf16_f32 (3 packs + 2 shifts vs 9x4-op f2bf).
    auto evalScatter = [&]() {
        char* rb0 = ldsb + srg * ROWB + sd * 2;
        #pragma unroll
        for (int it = 0; it < 8; ++it) {
            const float v = xv[it];
            const float u = fmaf(v, ih, nihg0);
            const float fm = floorf(u);
            const int m = (int)fm;
            const float t = u - fm;
            const float t2 = t * t;
            const float w0 = t2 * t;
            const float w1 = fmaf(fmaf(fmaf(-3.f, t, 3.f), t, 3.f), t, 1.f);
            const float w2 = fmaf(fmaf(3.f, t, -6.f) * t, t, 4.f);
            const float omt = 1.f - t;
            const float w3 = omt * omt * omt;
            const float den = 1.f + __expf(-v);
            float inv; asm("v_rcp_f32 %0, %1" : "=v"(inv) : "v"(den));
            const float sil = v * inv;
            unsigned p01, p23, ps;
            asm("v_cvt_pk_bf16_f32 %0, %1, %2" : "=v"(p01) : "v"(w0), "v"(w1));
            asm("v_cvt_pk_bf16_f32 %0, %1, %2" : "=v"(p23) : "v"(w2), "v"(w3));
            asm("v_cvt_pk_bf16_f32 %0, %1, %2" : "=v"(ps)  : "v"(sil), "v"(sil));
            const unsigned h1 = p01 >> 16, h3 = p23 >> 16;
            char* rb = rb0 + it * 16 * ROWB;          // imm-foldable (it*9344 < 64K)
            *(unsigned short*)rb = (unsigned short)ps;            // c = 0 (silu)
            #pragma unroll
            for (int s = 0; s < 8; ++s) {             // slot (m-s)&7: permutation of [0,7]
                const int ms = m - s;
                unsigned wv = 0u;
                if (s <= 3) {
                    const unsigned wsel = (s == 0) ? p01 : (s == 1) ? h1 : (s == 2) ? p23 : h3;
                    wv = ((unsigned)ms <= 7u) ? wsel : 0u;
                }
                *(unsigned short*)(rb + (((unsigned)ms & 7u) << 6) + 64) = (unsigned short)wv;
            }
        }
    };

    loadX(db0);
    #pragma unroll 1
    for (int db = db0; db < db1; ++db) {
        __syncthreads();               // all waves done reading previous chunk
        evalScatter();
        if (db + 1 < db1) loadX(db + 1);   // overlaps with MFMA phase below
        __syncthreads();               // chunk ready

        // MFMA phase: 9 units; software-pipelined B (next-unit prefetch in regs)
        const char* arow = ldsb + (rp * 32 + rr) * ROWB + q * 16;
        const char* bb = wpb + (size_t)db * 92160 + nh * 5120 + l * 16;
        bf16x8 bn[5];
        #pragma unroll
        for (int nt = 0; nt < 5; ++nt) bn[nt] = *(const bf16x8*)(bb + nt * 1024);
        #pragma unroll
        for (int c = 0; c < 9; ++c) {
            bf16x8 bc[5];
            #pragma unroll
            for (int nt = 0; nt < 5; ++nt) bc[nt] = bn[nt];
            if (c < 8) {
                const char* bnx = bb + (c + 1) * 10240;
                #pragma unroll
                for (int nt = 0; nt < 5; ++nt) bn[nt] = *(const bf16x8*)(bnx + nt * 1024);
            }
            const bf16x8 a0 = *(const bf16x8*)(arow + c * 64);
            const bf16x8 a1 = *(const bf16x8*)(arow + 16 * ROWB + c * 64);
            #pragma unroll
            for (int nt = 0; nt < 5; ++nt) {
                acc[0][nt] = __builtin_amdgcn_mfma_f32_16x16x32_bf16(a0, bc[nt], acc[0][nt], 0, 0, 0);
                acc[1][nt] = __builtin_amdgcn_mfma_f32_16x16x32_bf16(a1, bc[nt], acc[1][nt], 0, 0, 0);
            }
        }
    }

    // ---- direct store: C/D 16x16: row = q*4+ii, col = rr ----
    float* pp = part + (size_t)y * BATCH * NOUTC;
    #pragma unroll
    for (int rg = 0; rg < 2; ++rg) {
        #pragma unroll
        for (int ntl = 0; ntl < 5; ++ntl) {
            const int col = (nh * 5 + ntl) * 16 + rr;
            #pragma unroll
            for (int ii = 0; ii < 4; ++ii)
                pp[(size_t)(row0g + (rp * 2 + rg) * 16 + q * 4 + ii) * NOUTC + col] = acc[rg][ntl][ii];
        }
    }
}

// ---------------- epilogue MLP: sum partials, tanh -> 16x8 -> tanh -> 8x1 ----
__global__ void k_epi(const float* __restrict__ part, const float* __restrict__ w1,
                      const float* __restrict__ b1, const float* __restrict__ w2,
                      const float* __restrict__ b2, float* __restrict__ out) {
    int t = blockIdx.x * blockDim.x + threadIdx.x;
    if (t >= BATCH * HEADS) return;
    int b = t / HEADS;
    int h = t - b * HEADS;
    const f32x4* P = (const f32x4*)part;
    const int vbase = b * (NOUTC / 4) + h * 4;
    float y[16];
    #pragma unroll
    for (int c4 = 0; c4 < 4; ++c4) {
        f32x4 v = P[vbase + c4];
        #pragma unroll
        for (int s = 1; s < KSPLIT; ++s) {
            f32x4 v2 = P[(size_t)s * BATCH * (NOUTC / 4) + vbase + c4];
            v.x += v2.x; v.y += v2.y; v.z += v2.z; v.w += v2.w;
        }
        y[c4 * 4 + 0] = tanhf(v.x); y[c4 * 4 + 1] = tanhf(v.y);
        y[c4 * 4 + 2] = tanhf(v.z); y[c4 * 4 + 3] = tanhf(v.w);
    }
    float oacc = b2[h];
    #pragma unroll
    for (int p = 0; p < 8; ++p) {
        float a = b1[h * 8 + p];
        const float* wr = w1 + ((size_t)h * 8 + p) * 16;
        #pragma unroll
        for (int o = 0; o < 16; ++o) a = fmaf(y[o], wr[o], a);
        oacc = fmaf(tanhf(a), w2[h * 8 + p], oacc);
    }
    out[t] = oacc;
}

extern "C" void kernel_launch(void* const* d_in, const int* in_sizes, int n_in,
                              void* d_out, int out_size, void* d_ws, size_t ws_size,
                              hipStream_t stream) {
    const float* x          = (const float*)d_in[0];
    const float* gridp      = (const float*)d_in[1];
    const float* coef       = (const float*)d_in[2];
    const float* scale_base = (const float*)d_in[3];
    const float* scale_sp   = (const float*)d_in[4];
    const float* mask       = (const float*)d_in[5];
    const float* w1         = (const float*)d_in[6];
    const float* b1         = (const float*)d_in[7];
    const float* w2         = (const float*)d_in[8];
    const float* b2         = (const float*)d_in[9];
    float* out = (float*)d_out;

    char* ws = (char*)d_ws;
    float* part        = (float*)ws;                          // 4*16384*160*4 = 41,943,040 B
    unsigned short* Wp = (unsigned short*)(ws + 41943040);    // 225*32*160*2  =  2,304,000 B

    k_wprep<<<dim3((NUNITS * 32 * NOUTC + 255) / 256), dim3(256), 0, stream>>>(coef, scale_base, scale_sp, mask, Wp);
    k_fused<<<dim3(BATCH / MROWS, KSPLIT), dim3(512), 0, stream>>>(x, gridp, Wp, part);
    k_epi  <<<dim3((BATCH * HEADS + 255) / 256), dim3(256), 0, stream>>>(part, w1, b1, w2, b2, out);
}